// Round 1
// baseline (1678.186 us; speedup 1.0000x reference)
//
#include <hip/hip_runtime.h>
#include <hip/hip_bf16.h>
#include <math.h>

#define N_NODES 100000
#define N_EDGES 3200000
#define IN_DIM  512
#define HID     256

// ---------------------------------------------------------------------------
// K0: Wfused = W2 @ fc1_W  [256x32], bfused = b2 @ fc1_W + fc1_b  [32]
// grid 8 x 256
__global__ __launch_bounds__(256) void fuse_weights(
    const float* __restrict__ W2, const float* __restrict__ fc1W,
    const float* __restrict__ b2, const float* __restrict__ fc1b,
    float* __restrict__ Wf, float* __restrict__ bf) {
  int tid = threadIdx.x;
  int i = blockIdx.x * 32 + (tid >> 3);   // 0..255
  int jg = (tid & 7) * 4;
  float4 acc = {0.f, 0.f, 0.f, 0.f};
  for (int k = 0; k < HID; k++) {
    float w = W2[i * HID + k];
    float4 f = *(const float4*)(fc1W + k * 32 + jg);
    acc.x += w * f.x; acc.y += w * f.y; acc.z += w * f.z; acc.w += w * f.w;
  }
  *(float4*)(Wf + i * 32 + jg) = acc;
  if (blockIdx.x == 0 && tid < 32) {
    float s = fc1b[tid];
    for (int k = 0; k < HID; k++) s += b2[k] * fc1W[k * 32 + tid];
    bf[tid] = s;
  }
}

// ---------------------------------------------------------------------------
// K1: histogram of edge destination rows
__global__ __launch_bounds__(256) void hist_kernel(
    const int* __restrict__ rows, int* __restrict__ cnt, int n) {
  int i = blockIdx.x * 256 + threadIdx.x;
  if (i < n) atomicAdd(&cnt[rows[i]], 1);
}

// ---------------------------------------------------------------------------
// K2: single-block exclusive scan (1024 threads, shuffle-based)
__global__ __launch_bounds__(1024) void exscan_kernel(
    const int* __restrict__ cnt, int* __restrict__ rowptr,
    int* __restrict__ cursor, int n) {
  __shared__ int wsum[16];
  __shared__ int carry_s;
  int tid = threadIdx.x, lane = tid & 63, wid = tid >> 6;
  if (tid == 0) carry_s = 0;
  __syncthreads();
  for (int base = 0; base < n; base += 1024) {
    int i = base + tid;
    int v = (i < n) ? cnt[i] : 0;
    int x = v;
    #pragma unroll
    for (int d = 1; d < 64; d <<= 1) {
      int y = __shfl_up(x, d, 64);
      if (lane >= d) x += y;
    }
    if (lane == 63) wsum[wid] = x;
    __syncthreads();
    if (wid == 0 && lane < 16) {
      int s = wsum[lane];
      #pragma unroll
      for (int d = 1; d < 16; d <<= 1) {
        int y = __shfl_up(s, d, 64);
        if (lane >= d) s += y;
      }
      wsum[lane] = s;   // inclusive over wave sums
    }
    __syncthreads();
    int woff = (wid == 0) ? 0 : wsum[wid - 1];
    int carry = carry_s;
    int excl = carry + woff + x - v;
    if (i < n) { rowptr[i] = excl; cursor[i] = excl; }
    int total = wsum[15];
    __syncthreads();
    if (tid == 0) carry_s = carry + total;
    __syncthreads();
  }
  if (tid == 0) rowptr[n] = carry_s;
}

// ---------------------------------------------------------------------------
// K3: scatter edges into CSR (packed col+val, 8 B per edge)
__global__ __launch_bounds__(256) void scatter_kernel(
    const int* __restrict__ rows, const int* __restrict__ cols,
    const float* __restrict__ vals, int* __restrict__ cursor,
    int2* __restrict__ cv, int n) {
  int i = blockIdx.x * 256 + threadIdx.x;
  if (i < n) {
    int r = rows[i];
    int p = atomicAdd(&cursor[r], 1);
    int2 e;
    e.x = cols[i];
    e.y = __float_as_int(vals[i]);
    cv[p] = e;
  }
}

// ---------------------------------------------------------------------------
// K4: S1 = X @ W1   (fp32 tiled sgemm, M=100000 K=512 N=256)
// BM=128 BN=128 BK=16, block 256, thread tile 8x8
__global__ __launch_bounds__(256) void sgemm_kernel(
    const float* __restrict__ A, const float* __restrict__ B,
    float* __restrict__ C, int M, int N, int K) {
  __shared__ float As[16][132];   // A^T tile, padded (132*4 B rows keep 16B align)
  __shared__ float Bs[16][128];
  int tid = threadIdx.x;
  int bm = blockIdx.x * 128;
  int bn = blockIdx.y * 128;
  int tx = tid & 15;   // N dir
  int ty = tid >> 4;   // M dir
  float acc[8][8] = {};
  for (int k0 = 0; k0 < K; k0 += 16) {
    // load A tile: 128 rows x 16 k = 512 float4, 2 per thread
    #pragma unroll
    for (int i = 0; i < 2; i++) {
      int idx = tid + i * 256;
      int r = idx >> 2, q = idx & 3;
      float4 av = {0.f, 0.f, 0.f, 0.f};
      if (bm + r < M)
        av = *(const float4*)(A + (size_t)(bm + r) * K + k0 + q * 4);
      As[q * 4 + 0][r] = av.x;
      As[q * 4 + 1][r] = av.y;
      As[q * 4 + 2][r] = av.z;
      As[q * 4 + 3][r] = av.w;
    }
    // load B tile: 16 k x 128 n = 512 float4, 2 per thread
    #pragma unroll
    for (int i = 0; i < 2; i++) {
      int idx = tid + i * 256;
      int kk = idx >> 5, c = idx & 31;
      *(float4*)(&Bs[kk][c * 4]) =
          *(const float4*)(B + (size_t)(k0 + kk) * N + bn + c * 4);
    }
    __syncthreads();
    #pragma unroll
    for (int k = 0; k < 16; k++) {
      float a[8], b[8];
      *(float4*)&a[0] = *(const float4*)&As[k][ty * 4];
      *(float4*)&a[4] = *(const float4*)&As[k][ty * 4 + 64];
      *(float4*)&b[0] = *(const float4*)&Bs[k][tx * 4];
      *(float4*)&b[4] = *(const float4*)&Bs[k][tx * 4 + 64];
      #pragma unroll
      for (int i = 0; i < 8; i++)
        #pragma unroll
        for (int j = 0; j < 8; j++)
          acc[i][j] += a[i] * b[j];
    }
    __syncthreads();
  }
  #pragma unroll
  for (int ih = 0; ih < 2; ih++) {
    #pragma unroll
    for (int i = 0; i < 4; i++) {
      int r = bm + ih * 64 + ty * 4 + i;
      if (r >= M) continue;
      #pragma unroll
      for (int jh = 0; jh < 2; jh++) {
        float4 o;
        o.x = acc[ih * 4 + i][jh * 4 + 0];
        o.y = acc[ih * 4 + i][jh * 4 + 1];
        o.z = acc[ih * 4 + i][jh * 4 + 2];
        o.w = acc[ih * 4 + i][jh * 4 + 3];
        *(float4*)(C + (size_t)r * N + bn + jh * 64 + tx * 4) = o;
      }
    }
  }
}

// ---------------------------------------------------------------------------
// K5: H = relu(A_sp @ S1 + b1), CSR, one wave per row, D=256 (float4/lane)
__global__ __launch_bounds__(256) void spmm256_kernel(
    const int* __restrict__ rowptr, const int2* __restrict__ cv,
    const float* __restrict__ S, const float* __restrict__ bias,
    float* __restrict__ H, int nrows) {
  int row = blockIdx.x * 4 + (threadIdx.x >> 6);
  int lane = threadIdx.x & 63;
  if (row >= nrows) return;
  int start = rowptr[row], end = rowptr[row + 1];
  float4 acc = {0.f, 0.f, 0.f, 0.f};
  int j = start;
  for (; j + 1 < end; j += 2) {
    int2 e0 = cv[j];
    int2 e1 = cv[j + 1];
    float v0 = __int_as_float(e0.y);
    float v1 = __int_as_float(e1.y);
    float4 s0 = *(const float4*)(S + (size_t)e0.x * HID + lane * 4);
    float4 s1 = *(const float4*)(S + (size_t)e1.x * HID + lane * 4);
    acc.x += v0 * s0.x; acc.y += v0 * s0.y; acc.z += v0 * s0.z; acc.w += v0 * s0.w;
    acc.x += v1 * s1.x; acc.y += v1 * s1.y; acc.z += v1 * s1.z; acc.w += v1 * s1.w;
  }
  if (j < end) {
    int2 e0 = cv[j];
    float v0 = __int_as_float(e0.y);
    float4 s0 = *(const float4*)(S + (size_t)e0.x * HID + lane * 4);
    acc.x += v0 * s0.x; acc.y += v0 * s0.y; acc.z += v0 * s0.z; acc.w += v0 * s0.w;
  }
  float4 b = *(const float4*)(bias + lane * 4);
  acc.x = fmaxf(acc.x + b.x, 0.f);
  acc.y = fmaxf(acc.y + b.y, 0.f);
  acc.z = fmaxf(acc.z + b.z, 0.f);
  acc.w = fmaxf(acc.w + b.w, 0.f);
  *(float4*)(H + (size_t)row * HID + lane * 4) = acc;
}

// ---------------------------------------------------------------------------
// K6: S2 = H @ Wfused   [100000x256]@[256x32], Wfused in LDS
// block 256 -> 32 rows/block; thread = (row, 4-col group)
__global__ __launch_bounds__(256) void gemm_small_kernel(
    const float* __restrict__ H, const float* __restrict__ Wf,
    float* __restrict__ S2, int nrows) {
  __shared__ float Wl[HID * 32];
  int tid = threadIdx.x;
  for (int i = tid; i < HID * 32 / 4; i += 256)
    ((float4*)Wl)[i] = ((const float4*)Wf)[i];
  __syncthreads();
  int row = blockIdx.x * 32 + (tid >> 3);
  int cg = (tid & 7) * 4;
  if (row >= nrows) return;
  const float* hrow = H + (size_t)row * HID;
  float4 acc = {0.f, 0.f, 0.f, 0.f};
  for (int k4 = 0; k4 < HID / 4; k4++) {
    float4 x = *(const float4*)(hrow + k4 * 4);
    float xs[4] = {x.x, x.y, x.z, x.w};
    #pragma unroll
    for (int jj = 0; jj < 4; jj++) {
      float4 w = *(const float4*)(&Wl[(k4 * 4 + jj) * 32 + cg]);
      acc.x += xs[jj] * w.x; acc.y += xs[jj] * w.y;
      acc.z += xs[jj] * w.z; acc.w += xs[jj] * w.w;
    }
  }
  *(float4*)(S2 + (size_t)row * 32 + cg) = acc;
}

// ---------------------------------------------------------------------------
// K7: fused: t = A_sp @ S2 + bfused; h_a = relu(t); z = h_a@fc2W + fc2b;
//     out = log_softmax(z).  32 lanes per row, D=32.
__global__ __launch_bounds__(256) void spmm32_out_kernel(
    const int* __restrict__ rowptr, const int2* __restrict__ cv,
    const float* __restrict__ S2, const float* __restrict__ bf,
    const float* __restrict__ fc2W, const float* __restrict__ fc2b,
    float* __restrict__ out, int nrows) {
  int sub = threadIdx.x >> 5;
  int lane32 = threadIdx.x & 31;
  int row = blockIdx.x * 8 + sub;
  if (row >= nrows) return;
  int start = rowptr[row], end = rowptr[row + 1];
  float acc = 0.f;
  int j = start;
  for (; j + 1 < end; j += 2) {
    int2 e0 = cv[j];
    int2 e1 = cv[j + 1];
    float s0 = S2[(size_t)e0.x * 32 + lane32];
    float s1 = S2[(size_t)e1.x * 32 + lane32];
    acc += __int_as_float(e0.y) * s0;
    acc += __int_as_float(e1.y) * s1;
  }
  if (j < end) {
    int2 e0 = cv[j];
    acc += __int_as_float(e0.y) * S2[(size_t)e0.x * 32 + lane32];
  }
  float h = fmaxf(acc + bf[lane32], 0.f);
  float z0p = h * fc2W[lane32 * 2 + 0];
  float z1p = h * fc2W[lane32 * 2 + 1];
  #pragma unroll
  for (int m = 16; m >= 1; m >>= 1) {
    z0p += __shfl_xor(z0p, m, 32);
    z1p += __shfl_xor(z1p, m, 32);
  }
  if (lane32 == 0) {
    float z0 = z0p + fc2b[0];
    float z1 = z1p + fc2b[1];
    float mx = fmaxf(z0, z1);
    float lse = mx + logf(expf(z0 - mx) + expf(z1 - mx));
    float2 o = {z0 - lse, z1 - lse};
    *(float2*)(out + (size_t)row * 2) = o;
  }
}

// ---------------------------------------------------------------------------
extern "C" void kernel_launch(void* const* d_in, const int* in_sizes, int n_in,
                              void* d_out, int out_size, void* d_ws, size_t ws_size,
                              hipStream_t stream) {
  const float* X     = (const float*)d_in[0];
  const int*   erow  = (const int*)d_in[1];
  const int*   ecol  = (const int*)d_in[2];
  const float* eval_ = (const float*)d_in[3];
  const float* W1    = (const float*)d_in[4];
  const float* b1    = (const float*)d_in[5];
  const float* W2    = (const float*)d_in[6];
  const float* b2    = (const float*)d_in[7];
  const float* fc1W  = (const float*)d_in[8];
  const float* fc1b  = (const float*)d_in[9];
  const float* fc2W  = (const float*)d_in[10];
  const float* fc2b  = (const float*)d_in[11];
  float* out = (float*)d_out;

  // workspace carve-up (256 B aligned)
  size_t off = 0;
  auto alloc = [&](size_t bytes) {
    void* p = (char*)d_ws + off;
    off += (bytes + 255) & ~(size_t)255;
    return p;
  };
  float* Wf     = (float*)alloc((size_t)HID * 32 * 4);
  float* bf     = (float*)alloc(32 * 4);
  int*   cnt    = (int*)alloc((size_t)N_NODES * 4);
  int*   rowptr = (int*)alloc((size_t)(N_NODES + 1) * 4);
  int*   cursor = (int*)alloc((size_t)(N_NODES + 1) * 4);
  int2*  cv     = (int2*)alloc((size_t)N_EDGES * 8);
  float* S1     = (float*)alloc((size_t)N_NODES * HID * 4);
  float* H      = (float*)alloc((size_t)N_NODES * HID * 4);
  float* S2     = (float*)alloc((size_t)N_NODES * 32 * 4);
  (void)ws_size; (void)n_in; (void)in_sizes; (void)out_size;

  hipMemsetAsync(cnt, 0, (size_t)N_NODES * 4, stream);

  fuse_weights<<<8, 256, 0, stream>>>(W2, fc1W, b2, fc1b, Wf, bf);

  hist_kernel<<<(N_EDGES + 255) / 256, 256, 0, stream>>>(erow, cnt, N_EDGES);
  exscan_kernel<<<1, 1024, 0, stream>>>(cnt, rowptr, cursor, N_NODES);
  scatter_kernel<<<(N_EDGES + 255) / 256, 256, 0, stream>>>(
      erow, ecol, eval_, cursor, cv, N_EDGES);

  dim3 ggrid((N_NODES + 127) / 128, HID / 128);
  sgemm_kernel<<<ggrid, 256, 0, stream>>>(X, W1, S1, N_NODES, HID, IN_DIM);

  spmm256_kernel<<<(N_NODES + 3) / 4, 256, 0, stream>>>(
      rowptr, cv, S1, b1, H, N_NODES);

  gemm_small_kernel<<<(N_NODES + 31) / 32, 256, 0, stream>>>(H, Wf, S2, N_NODES);

  spmm32_out_kernel<<<(N_NODES + 7) / 8, 256, 0, stream>>>(
      rowptr, cv, S2, bf, fc2W, fc2b, out, N_NODES);
}

// Round 2
// 1133.940 us; speedup vs baseline: 1.4800x; 1.4800x over previous
//
#include <hip/hip_runtime.h>
#include <hip/hip_bf16.h>
#include <math.h>

#define N_NODES 100000
#define N_EDGES 3200000
#define IN_DIM  512
#define HID     256

typedef __attribute__((ext_vector_type(8))) short bf16x8;
typedef __attribute__((ext_vector_type(4))) float f32x4;

__device__ __forceinline__ ushort f2bf(float f) {
  // round-to-nearest-even fp32 -> bf16 (finite inputs)
  uint x = __float_as_uint(f);
  return (ushort)((x + 0x7fffu + ((x >> 16) & 1u)) >> 16);
}
__device__ __forceinline__ float bf2f(ushort u) {
  return __uint_as_float(((uint)u) << 16);
}

// ---------------------------------------------------------------------------
// K0: Wfused = W2 @ fc1_W  [256x32], bfused = b2 @ fc1_W + fc1_b  [32]
__global__ __launch_bounds__(256) void fuse_weights(
    const float* __restrict__ W2, const float* __restrict__ fc1W,
    const float* __restrict__ b2, const float* __restrict__ fc1b,
    float* __restrict__ Wf, float* __restrict__ bf) {
  int tid = threadIdx.x;
  int i = blockIdx.x * 32 + (tid >> 3);   // 0..255
  int jg = (tid & 7) * 4;
  float4 acc = {0.f, 0.f, 0.f, 0.f};
  for (int k = 0; k < HID; k++) {
    float w = W2[i * HID + k];
    float4 f = *(const float4*)(fc1W + k * 32 + jg);
    acc.x += w * f.x; acc.y += w * f.y; acc.z += w * f.z; acc.w += w * f.w;
  }
  *(float4*)(Wf + i * 32 + jg) = acc;
  if (blockIdx.x == 0 && tid < 32) {
    float s = fc1b[tid];
    for (int k = 0; k < HID; k++) s += b2[k] * fc1W[k * 32 + tid];
    bf[tid] = s;
  }
}

// ---------------------------------------------------------------------------
// K0b: W1T_bf16[n][k] = bf16(W1[k][n])   (256x512 from 512x256)
__global__ __launch_bounds__(256) void prep_w1t(
    const float* __restrict__ W1, ushort* __restrict__ W1T) {
  int n = blockIdx.x;          // 0..255
  for (int k = threadIdx.x; k < IN_DIM; k += 256)
    W1T[(size_t)n * IN_DIM + k] = f2bf(W1[(size_t)k * HID + n]);
}

// ---------------------------------------------------------------------------
// K1: histogram of edge destination rows
__global__ __launch_bounds__(256) void hist_kernel(
    const int* __restrict__ rows, int* __restrict__ cnt, int n) {
  int i = blockIdx.x * 256 + threadIdx.x;
  if (i < n) atomicAdd(&cnt[rows[i]], 1);
}

// ---------------------------------------------------------------------------
// K2a: per-block sums of cnt (256 elements/block)
__global__ __launch_bounds__(256) void blocksum_kernel(
    const int* __restrict__ cnt, int* __restrict__ bsum, int n) {
  int i = blockIdx.x * 256 + threadIdx.x;
  int v = (i < n) ? cnt[i] : 0;
  #pragma unroll
  for (int m = 1; m < 64; m <<= 1) v += __shfl_xor(v, m, 64);
  __shared__ int ws[4];
  if ((threadIdx.x & 63) == 0) ws[threadIdx.x >> 6] = v;
  __syncthreads();
  if (threadIdx.x == 0) bsum[blockIdx.x] = ws[0] + ws[1] + ws[2] + ws[3];
}

// K2b: exclusive scan of the (<=512) block sums, in place, single block
__global__ __launch_bounds__(512) void scanpart_kernel(
    int* __restrict__ bsum, int nb) {
  int tid = threadIdx.x, lane = tid & 63, wid = tid >> 6;
  int v = (tid < nb) ? bsum[tid] : 0;
  int x = v;
  #pragma unroll
  for (int d = 1; d < 64; d <<= 1) {
    int y = __shfl_up(x, d, 64);
    if (lane >= d) x += y;
  }
  __shared__ int ws[8];
  if (lane == 63) ws[wid] = x;
  __syncthreads();
  int woff = 0;
  for (int w = 0; w < wid; w++) woff += ws[w];
  if (tid < nb) bsum[tid] = woff + x - v;   // exclusive
}

// K2c: final scan: rowptr/cursor = bsum[block] + in-block exclusive scan
__global__ __launch_bounds__(256) void scanfinal_kernel(
    const int* __restrict__ cnt, const int* __restrict__ bsum,
    int* __restrict__ rowptr, int* __restrict__ cursor, int n) {
  int tid = threadIdx.x, lane = tid & 63, wid = tid >> 6;
  int i = blockIdx.x * 256 + tid;
  int v = (i < n) ? cnt[i] : 0;
  int x = v;
  #pragma unroll
  for (int d = 1; d < 64; d <<= 1) {
    int y = __shfl_up(x, d, 64);
    if (lane >= d) x += y;
  }
  __shared__ int ws[4];
  if (lane == 63) ws[wid] = x;
  __syncthreads();
  int woff = bsum[blockIdx.x];
  for (int w = 0; w < wid; w++) woff += ws[w];
  int excl = woff + x - v;
  if (i < n) { rowptr[i] = excl; cursor[i] = excl; }
  if (i == 0) rowptr[n] = N_EDGES;
}

// ---------------------------------------------------------------------------
// K3: scatter edges into CSR (packed col+val, 8 B per edge)
__global__ __launch_bounds__(256) void scatter_kernel(
    const int* __restrict__ rows, const int* __restrict__ cols,
    const float* __restrict__ vals, int* __restrict__ cursor,
    int2* __restrict__ cv, int n) {
  int i = blockIdx.x * 256 + threadIdx.x;
  if (i < n) {
    int r = rows[i];
    int p = atomicAdd(&cursor[r], 1);
    int2 e;
    e.x = cols[i];
    e.y = __float_as_int(vals[i]);
    cv[p] = e;
  }
}

// ---------------------------------------------------------------------------
// K4: S1_bf16 = bf16( X @ W1 )  via MFMA 16x16x32 bf16.
// M=100000, K=512, N=256. BM=128 BN=128 BK=32, block=256 (4 waves, 2x2).
// A staged fp32->bf16 inline; B from pre-transposed W1T bf16 [N][K].
__global__ __launch_bounds__(256) void gemm1_mfma(
    const float* __restrict__ A, const ushort* __restrict__ BT,
    ushort* __restrict__ C, int M) {
  __shared__ __align__(16) char smem[32768];
  ushort* As = (ushort*)smem;             // [128][40] bf16, padded stride 40
  ushort* Bs = (ushort*)(smem + 10240);   // [128][40] bf16 (n-major, k contiguous)
  int tid = threadIdx.x;
  int bm = blockIdx.x * 128;
  int bn = blockIdx.y * 128;
  int lane = tid & 63, wid = tid >> 6;
  int waveM = wid >> 1, waveN = wid & 1;
  int l16 = lane & 15, quad = lane >> 4;

  f32x4 acc[4][4] = {};

  int ar = tid >> 1;                 // A row within tile (0..127)
  int ac = (tid & 1) * 16;           // k offset (0 or 16)
  const float* aptr = A + (size_t)(bm + ar) * IN_DIM + ac;
  bool avalid = (bm + ar) < M;
  const ushort* bptr = BT + (size_t)(bn + ar) * IN_DIM + ac;  // same r/c split
  ushort* aw = As + ar * 40 + ac;
  ushort* bw = Bs + ar * 40 + ac;

  for (int k0 = 0; k0 < IN_DIM; k0 += 32) {
    // stage A: 4x float4 load -> bf16x4 LDS write
    #pragma unroll
    for (int i = 0; i < 4; i++) {
      float4 av = {0.f, 0.f, 0.f, 0.f};
      if (avalid) av = *(const float4*)(aptr + k0 + i * 4);
      ushort4 p;
      p.x = f2bf(av.x); p.y = f2bf(av.y); p.z = f2bf(av.z); p.w = f2bf(av.w);
      *(ushort4*)(aw + i * 4) = p;
    }
    // stage B: 2x 16B copies (already bf16, k-contiguous)
    *(int4*)(bw)     = *(const int4*)(bptr + k0);
    *(int4*)(bw + 8) = *(const int4*)(bptr + k0 + 8);
    __syncthreads();

    bf16x8 af[4], bfv[4];
    #pragma unroll
    for (int mi = 0; mi < 4; mi++)
      af[mi] = *(const bf16x8*)(As + (waveM * 64 + mi * 16 + l16) * 40 + quad * 8);
    #pragma unroll
    for (int ni = 0; ni < 4; ni++)
      bfv[ni] = *(const bf16x8*)(Bs + (waveN * 64 + ni * 16 + l16) * 40 + quad * 8);
    #pragma unroll
    for (int mi = 0; mi < 4; mi++)
      #pragma unroll
      for (int ni = 0; ni < 4; ni++)
        acc[mi][ni] = __builtin_amdgcn_mfma_f32_16x16x32_bf16(
            af[mi], bfv[ni], acc[mi][ni], 0, 0, 0);
    __syncthreads();
  }

  // epilogue: repack through LDS (aliases As/Bs; all reads done) then
  // fully-coalesced 16B bf16 stores.
  ushort* Cs = (ushort*)smem;   // [128][128]
  #pragma unroll
  for (int mi = 0; mi < 4; mi++)
    #pragma unroll
    for (int ni = 0; ni < 4; ni++)
      #pragma unroll
      for (int r = 0; r < 4; r++)
        Cs[(waveM * 64 + mi * 16 + quad * 4 + r) * 128 + waveN * 64 + ni * 16 + l16] =
            f2bf(acc[mi][ni][r]);
  __syncthreads();
  #pragma unroll
  for (int i = 0; i < 8; i++) {
    int f = tid + i * 256;         // 0..2047
    int row = f >> 4, v4 = f & 15;
    if (bm + row < M)
      *(int4*)(C + (size_t)(bm + row) * HID + bn + v4 * 8) =
          *(const int4*)(Cs + row * 128 + v4 * 8);
  }
}

// ---------------------------------------------------------------------------
// K5: H_bf16 = bf16(relu(A_sp @ S1_bf16 + b1)), one wave per row, D=256
__global__ __launch_bounds__(256) void spmm256_kernel(
    const int* __restrict__ rowptr, const int2* __restrict__ cv,
    const ushort* __restrict__ S, const float* __restrict__ bias,
    ushort* __restrict__ H, int nrows) {
  int row = blockIdx.x * 4 + (threadIdx.x >> 6);
  int lane = threadIdx.x & 63;
  if (row >= nrows) return;
  int start = rowptr[row], end = rowptr[row + 1];
  float a0 = 0.f, a1 = 0.f, a2 = 0.f, a3 = 0.f;
  int j = start;
  for (; j + 1 < end; j += 2) {
    int2 e0 = cv[j];
    int2 e1 = cv[j + 1];
    float v0 = __int_as_float(e0.y);
    float v1 = __int_as_float(e1.y);
    ushort4 s0 = *(const ushort4*)(S + (size_t)e0.x * HID + lane * 4);
    ushort4 s1 = *(const ushort4*)(S + (size_t)e1.x * HID + lane * 4);
    a0 += v0 * bf2f(s0.x); a1 += v0 * bf2f(s0.y);
    a2 += v0 * bf2f(s0.z); a3 += v0 * bf2f(s0.w);
    a0 += v1 * bf2f(s1.x); a1 += v1 * bf2f(s1.y);
    a2 += v1 * bf2f(s1.z); a3 += v1 * bf2f(s1.w);
  }
  if (j < end) {
    int2 e0 = cv[j];
    float v0 = __int_as_float(e0.y);
    ushort4 s0 = *(const ushort4*)(S + (size_t)e0.x * HID + lane * 4);
    a0 += v0 * bf2f(s0.x); a1 += v0 * bf2f(s0.y);
    a2 += v0 * bf2f(s0.z); a3 += v0 * bf2f(s0.w);
  }
  float4 b = *(const float4*)(bias + lane * 4);
  ushort4 o;
  o.x = f2bf(fmaxf(a0 + b.x, 0.f));
  o.y = f2bf(fmaxf(a1 + b.y, 0.f));
  o.z = f2bf(fmaxf(a2 + b.z, 0.f));
  o.w = f2bf(fmaxf(a3 + b.w, 0.f));
  *(ushort4*)(H + (size_t)row * HID + lane * 4) = o;
}

// ---------------------------------------------------------------------------
// K6: S2 = H_bf16 @ Wfused   [100000x256]@[256x32], Wfused in LDS
__global__ __launch_bounds__(256) void gemm_small_kernel(
    const ushort* __restrict__ H, const float* __restrict__ Wf,
    float* __restrict__ S2, int nrows) {
  __shared__ float Wl[HID * 32];
  int tid = threadIdx.x;
  for (int i = tid; i < HID * 32 / 4; i += 256)
    ((float4*)Wl)[i] = ((const float4*)Wf)[i];
  __syncthreads();
  int row = blockIdx.x * 32 + (tid >> 3);
  int cg = (tid & 7) * 4;
  if (row >= nrows) return;
  const ushort* hrow = H + (size_t)row * HID;
  float4 acc = {0.f, 0.f, 0.f, 0.f};
  for (int k4 = 0; k4 < HID / 4; k4++) {
    ushort4 xu = *(const ushort4*)(hrow + k4 * 4);
    float xs[4] = {bf2f(xu.x), bf2f(xu.y), bf2f(xu.z), bf2f(xu.w)};
    #pragma unroll
    for (int jj = 0; jj < 4; jj++) {
      float4 w = *(const float4*)(&Wl[(k4 * 4 + jj) * 32 + cg]);
      acc.x += xs[jj] * w.x; acc.y += xs[jj] * w.y;
      acc.z += xs[jj] * w.z; acc.w += xs[jj] * w.w;
    }
  }
  *(float4*)(S2 + (size_t)row * 32 + cg) = acc;
}

// ---------------------------------------------------------------------------
// K7: fused: t = A_sp @ S2 + bfused; h_a = relu(t); z = h_a@fc2W + fc2b;
//     out = log_softmax(z).  32 lanes per row, D=32.
__global__ __launch_bounds__(256) void spmm32_out_kernel(
    const int* __restrict__ rowptr, const int2* __restrict__ cv,
    const float* __restrict__ S2, const float* __restrict__ bf,
    const float* __restrict__ fc2W, const float* __restrict__ fc2b,
    float* __restrict__ out, int nrows) {
  int sub = threadIdx.x >> 5;
  int lane32 = threadIdx.x & 31;
  int row = blockIdx.x * 8 + sub;
  if (row >= nrows) return;
  int start = rowptr[row], end = rowptr[row + 1];
  float acc = 0.f;
  int j = start;
  for (; j + 1 < end; j += 2) {
    int2 e0 = cv[j];
    int2 e1 = cv[j + 1];
    float s0 = S2[(size_t)e0.x * 32 + lane32];
    float s1 = S2[(size_t)e1.x * 32 + lane32];
    acc += __int_as_float(e0.y) * s0;
    acc += __int_as_float(e1.y) * s1;
  }
  if (j < end) {
    int2 e0 = cv[j];
    acc += __int_as_float(e0.y) * S2[(size_t)e0.x * 32 + lane32];
  }
  float h = fmaxf(acc + bf[lane32], 0.f);
  float z0p = h * fc2W[lane32 * 2 + 0];
  float z1p = h * fc2W[lane32 * 2 + 1];
  #pragma unroll
  for (int m = 16; m >= 1; m >>= 1) {
    z0p += __shfl_xor(z0p, m, 32);
    z1p += __shfl_xor(z1p, m, 32);
  }
  if (lane32 == 0) {
    float z0 = z0p + fc2b[0];
    float z1 = z1p + fc2b[1];
    float mx = fmaxf(z0, z1);
    float lse = mx + logf(expf(z0 - mx) + expf(z1 - mx));
    float2 o = {z0 - lse, z1 - lse};
    *(float2*)(out + (size_t)row * 2) = o;
  }
}

// ---------------------------------------------------------------------------
extern "C" void kernel_launch(void* const* d_in, const int* in_sizes, int n_in,
                              void* d_out, int out_size, void* d_ws, size_t ws_size,
                              hipStream_t stream) {
  const float* X     = (const float*)d_in[0];
  const int*   erow  = (const int*)d_in[1];
  const int*   ecol  = (const int*)d_in[2];
  const float* eval_ = (const float*)d_in[3];
  const float* W1    = (const float*)d_in[4];
  const float* b1    = (const float*)d_in[5];
  const float* W2    = (const float*)d_in[6];
  const float* b2    = (const float*)d_in[7];
  const float* fc1W  = (const float*)d_in[8];
  const float* fc1b  = (const float*)d_in[9];
  const float* fc2W  = (const float*)d_in[10];
  const float* fc2b  = (const float*)d_in[11];
  float* out = (float*)d_out;

  size_t off = 0;
  auto alloc = [&](size_t bytes) {
    void* p = (char*)d_ws + off;
    off += (bytes + 255) & ~(size_t)255;
    return p;
  };
  float*  Wf     = (float*)alloc((size_t)HID * 32 * 4);
  float*  bf     = (float*)alloc(32 * 4);
  int*    cnt    = (int*)alloc((size_t)N_NODES * 4);
  int*    rowptr = (int*)alloc((size_t)(N_NODES + 1) * 4);
  int*    cursor = (int*)alloc((size_t)(N_NODES + 1) * 4);
  int*    bsum   = (int*)alloc((size_t)512 * 4);
  int2*   cv     = (int2*)alloc((size_t)N_EDGES * 8);
  ushort* W1T    = (ushort*)alloc((size_t)HID * IN_DIM * 2);
  ushort* S1b    = (ushort*)alloc((size_t)N_NODES * HID * 2);
  ushort* Hb     = (ushort*)alloc((size_t)N_NODES * HID * 2);
  float*  S2     = (float*)alloc((size_t)N_NODES * 32 * 4);
  (void)ws_size; (void)n_in; (void)in_sizes; (void)out_size;

  const int NBLK = (N_NODES + 255) / 256;   // 391

  hipMemsetAsync(cnt, 0, (size_t)N_NODES * 4, stream);

  fuse_weights<<<8, 256, 0, stream>>>(W2, fc1W, b2, fc1b, Wf, bf);
  prep_w1t<<<HID, 256, 0, stream>>>(W1, W1T);

  hist_kernel<<<(N_EDGES + 255) / 256, 256, 0, stream>>>(erow, cnt, N_EDGES);
  blocksum_kernel<<<NBLK, 256, 0, stream>>>(cnt, bsum, N_NODES);
  scanpart_kernel<<<1, 512, 0, stream>>>(bsum, NBLK);
  scanfinal_kernel<<<NBLK, 256, 0, stream>>>(cnt, bsum, rowptr, cursor, N_NODES);
  scatter_kernel<<<(N_EDGES + 255) / 256, 256, 0, stream>>>(
      erow, ecol, eval_, cursor, cv, N_EDGES);

  dim3 ggrid((N_NODES + 127) / 128, HID / 128);
  gemm1_mfma<<<ggrid, 256, 0, stream>>>(X, W1T, S1b, N_NODES);

  spmm256_kernel<<<(N_NODES + 3) / 4, 256, 0, stream>>>(
      rowptr, cv, S1b, b1, Hb, N_NODES);

  gemm_small_kernel<<<(N_NODES + 31) / 32, 256, 0, stream>>>(Hb, Wf, S2, N_NODES);

  spmm32_out_kernel<<<(N_NODES + 7) / 8, 256, 0, stream>>>(
      rowptr, cv, S2, bf, fc2W, fc2b, out, N_NODES);
}